// Round 1
// baseline (31.902 us; speedup 1.0000x reference)
//
#include <hip/hip_runtime.h>
#include <math.h>

#define NP   196   // patches per image
#define NC   10    // classes

// One block = one image. Thread p (<196) simulates patch p's two independent
// 2-qubit circuits, contracts the 4 features against W[:, 4p:4p+4] (float4,
// perfectly coalesced across threads), then block-reduces 10 logits and does
// log_softmax in the first wave.
__global__ __launch_bounds__(256) void quanv_fused(
    const float* __restrict__ x,      // (B, 784) row-major 28x28
    const float* __restrict__ theta,  // (2, 4)
    const float* __restrict__ W,      // (10, 784)
    const float* __restrict__ bias,   // (10,)
    float* __restrict__ out)          // (B, 10)
{
    __shared__ float s_th0[4], s_ct1[4], s_st1[4];
    __shared__ float s_part[4][NC];

    const int tid = threadIdx.x;
    const int img = blockIdx.x;

    if (tid < 4) {
        s_th0[tid] = theta[tid];               // layer-0 angle (absorbed into prep)
        float sv, cv;
        __sincosf(0.5f * theta[4 + tid], &sv, &cv);  // layer-1 rotation
        s_st1[tid] = sv;
        s_ct1[tid] = cv;
    }
    __syncthreads();

    float acc[NC];
#pragma unroll
    for (int c = 0; c < NC; ++c) acc[c] = 0.f;

    if (tid < NP) {
        const int i = tid / 14;
        const int j = tid - i * 14;
        const float* px = x + (size_t)img * 784 + i * 56 + j * 2;
        const float2 r0 = *(const float2*)(px);        // pixels (2i, 2j), (2i, 2j+1)
        const float2 r1 = *(const float2*)(px + 28);   // pixels (2i+1, 2j), (2i+1, 2j+1)

        float f[4];
        // --- pair A: wires 0,1 = pixels r0.x, r0.y ---
        {
            float sa, ca, sb, cb;
            __sincosf(0.5f * (r0.x + s_th0[0]), &sa, &ca);
            __sincosf(0.5f * (r0.y + s_th0[1]), &sb, &cb);
            const float ct0 = s_ct1[0], st0 = s_st1[0];
            const float ct1 = s_ct1[1], st1 = s_st1[1];
            // state after RY-layer0 + CNOT(0->1): [ca*cb, ca*sb, sa*sb, sa*cb]
            float p0 = ca * cb, p1 = ca * sb, p2 = sa * sb, p3 = sa * cb;
            // RY(theta1[0]) on qubit0: pairs (0,2),(1,3)
            float q0 = ct0 * p0 - st0 * p2, q2 = st0 * p0 + ct0 * p2;
            float q1 = ct0 * p1 - st0 * p3, q3 = st0 * p1 + ct0 * p3;
            // RY(theta1[1]) on qubit1: pairs (0,1),(2,3)
            float r0a = ct1 * q0 - st1 * q1, r1a = st1 * q0 + ct1 * q1;
            float r2a = ct1 * q2 - st1 * q3, r3a = st1 * q2 + ct1 * q3;
            // final CNOT(0->1) swaps amps 2,3 (affects only z1's sign pattern)
            float e0 = r0a * r0a, e1 = r1a * r1a, e2 = r2a * r2a, e3 = r3a * r3a;
            f[0] = (e0 + e1) - (e2 + e3);
            f[1] = (e0 - e1) + (e3 - e2);
        }
        // --- pair B: wires 2,3 = pixels r1.x, r1.y ---
        {
            float sa, ca, sb, cb;
            __sincosf(0.5f * (r1.x + s_th0[2]), &sa, &ca);
            __sincosf(0.5f * (r1.y + s_th0[3]), &sb, &cb);
            const float ct0 = s_ct1[2], st0 = s_st1[2];
            const float ct1 = s_ct1[3], st1 = s_st1[3];
            float p0 = ca * cb, p1 = ca * sb, p2 = sa * sb, p3 = sa * cb;
            float q0 = ct0 * p0 - st0 * p2, q2 = st0 * p0 + ct0 * p2;
            float q1 = ct0 * p1 - st0 * p3, q3 = st0 * p1 + ct0 * p3;
            float r0a = ct1 * q0 - st1 * q1, r1a = st1 * q0 + ct1 * q1;
            float r2a = ct1 * q2 - st1 * q3, r3a = st1 * q2 + ct1 * q3;
            float e0 = r0a * r0a, e1 = r1a * r1a, e2 = r2a * r2a, e3 = r3a * r3a;
            f[2] = (e0 + e1) - (e2 + e3);
            f[3] = (e0 - e1) + (e3 - e2);
        }

        // contract against W rows: W[c, 4p .. 4p+3] — coalesced float4 per class
#pragma unroll
        for (int c = 0; c < NC; ++c) {
            const float4 w4 = *(const float4*)(W + c * 784 + tid * 4);
            acc[c] = f[0] * w4.x + f[1] * w4.y + f[2] * w4.z + f[3] * w4.w;
        }
    }

    // block reduction of 10 logits: wave shuffle, then cross-wave via LDS
    const int lane = tid & 63;
    const int wv = tid >> 6;
#pragma unroll
    for (int c = 0; c < NC; ++c) {
        float v = acc[c];
        v += __shfl_down(v, 32);
        v += __shfl_down(v, 16);
        v += __shfl_down(v, 8);
        v += __shfl_down(v, 4);
        v += __shfl_down(v, 2);
        v += __shfl_down(v, 1);
        if (lane == 0) s_part[wv][c] = v;
    }
    __syncthreads();

    if (tid < 16) {
        float l = -INFINITY;
        if (tid < NC)
            l = s_part[0][tid] + s_part[1][tid] + s_part[2][tid] + s_part[3][tid]
                + bias[tid];
        float m = l;
        m = fmaxf(m, __shfl_xor(m, 8, 16));
        m = fmaxf(m, __shfl_xor(m, 4, 16));
        m = fmaxf(m, __shfl_xor(m, 2, 16));
        m = fmaxf(m, __shfl_xor(m, 1, 16));
        float e = (tid < NC) ? expf(l - m) : 0.f;
        float se = e;
        se += __shfl_xor(se, 8, 16);
        se += __shfl_xor(se, 4, 16);
        se += __shfl_xor(se, 2, 16);
        se += __shfl_xor(se, 1, 16);
        if (tid < NC) out[img * NC + tid] = l - m - logf(se);
    }
}

extern "C" void kernel_launch(void* const* d_in, const int* in_sizes, int n_in,
                              void* d_out, int out_size, void* d_ws, size_t ws_size,
                              hipStream_t stream) {
    const float* x     = (const float*)d_in[0];  // (B,1,28,28)
    const float* theta = (const float*)d_in[1];  // (2,4)
    const float* W     = (const float*)d_in[2];  // (10,784)
    const float* bias  = (const float*)d_in[3];  // (10,)
    float* out = (float*)d_out;                  // (B,10)
    const int B = in_sizes[0] / 784;
    quanv_fused<<<B, 256, 0, stream>>>(x, theta, W, bias, out);
}

// Round 2
// 17.035 us; speedup vs baseline: 1.8727x; 1.8727x over previous
//
#include <hip/hip_runtime.h>
#include <math.h>

#define NP 196   // patches per image
#define NC 10    // classes
// Block = 256 threads = 4 waves. Each wave owns TWO images (amortizes W loads).
// Lane l handles patches {l, l+64, l+128} (+ 192+l for l<4) for both images.
// Logit reduce = per-class 6-level xor-butterfly within the wave; afterwards
// every lane holds all 10 logits -> softmax fully in-register, no LDS stage.

__device__ __forceinline__ void sim_pair(float pxa, float pxb,
                                         float th0a, float th0b,
                                         float ct0, float st0,
                                         float ct1, float st1,
                                         float& z0, float& z1) {
    float sa, ca, sb, cb;
    __sincosf(0.5f * (pxa + th0a), &sa, &ca);
    __sincosf(0.5f * (pxb + th0b), &sb, &cb);
    // state after RY-layer0 + CNOT: [ca*cb, ca*sb, sa*sb, sa*cb]
    float p0 = ca * cb, p1 = ca * sb, p2 = sa * sb, p3 = sa * cb;
    float q0 = ct0 * p0 - st0 * p2, q2 = st0 * p0 + ct0 * p2;
    float q1 = ct0 * p1 - st0 * p3, q3 = st0 * p1 + ct0 * p3;
    float r0 = ct1 * q0 - st1 * q1, r1 = st1 * q0 + ct1 * q1;
    float r2 = ct1 * q2 - st1 * q3, r3 = st1 * q2 + ct1 * q3;
    float e0 = r0 * r0, e1 = r1 * r1, e2 = r2 * r2, e3 = r3 * r3;
    z0 = (e0 + e1) - (e2 + e3);
    z1 = (e0 - e1) + (e3 - e2);
}

__global__ __launch_bounds__(256) void quanv_fused(
    const float* __restrict__ x,      // (B, 784)
    const float* __restrict__ theta,  // (2, 4)
    const float* __restrict__ W,      // (10, 784)
    const float* __restrict__ bias,   // (10,)
    float* __restrict__ out,          // (B, 10)
    int B)
{
    __shared__ float s_th0[4], s_ct1[4], s_st1[4], s_bias[NC];
    const int tid = threadIdx.x;
    if (tid < 4) {
        s_th0[tid] = theta[tid];
        float sv, cv;
        __sincosf(0.5f * theta[4 + tid], &sv, &cv);
        s_st1[tid] = sv;
        s_ct1[tid] = cv;
    }
    if (tid < NC) s_bias[tid] = bias[tid];
    __syncthreads();

    const int lane = tid & 63;
    const int wave = blockIdx.x * 4 + (tid >> 6);
    const int imgA = wave * 2;
    if (imgA >= B) return;

    // broadcast circuit constants into registers once
    const float th00 = s_th0[0], th01 = s_th0[1], th02 = s_th0[2], th03 = s_th0[3];
    const float ctA0 = s_ct1[0], stA0 = s_st1[0], ctA1 = s_ct1[1], stA1 = s_st1[1];
    const float ctB0 = s_ct1[2], stB0 = s_st1[2], ctB1 = s_ct1[3], stB1 = s_st1[3];

    const float* xA = x + (size_t)imgA * 784;
    const float* xB = xA + 784;

    float accA[NC], accB[NC];
#pragma unroll
    for (int c = 0; c < NC; ++c) { accA[c] = 0.f; accB[c] = 0.f; }

#pragma unroll
    for (int k = 0; k < 4; ++k) {
        const int p = lane + 64 * k;
        if (k == 3 && p >= NP) break;   // only lanes 0-3 run the 4th slot
        const int i = p / 14;
        const int j = p - i * 14;
        const int off = i * 56 + j * 2;

        const float2 a0 = *(const float2*)(xA + off);
        const float2 a1 = *(const float2*)(xA + off + 28);
        const float2 b0 = *(const float2*)(xB + off);
        const float2 b1 = *(const float2*)(xB + off + 28);

        float fA[4], fB[4];
        sim_pair(a0.x, a0.y, th00, th01, ctA0, stA0, ctA1, stA1, fA[0], fA[1]);
        sim_pair(a1.x, a1.y, th02, th03, ctB0, stB0, ctB1, stB1, fA[2], fA[3]);
        sim_pair(b0.x, b0.y, th00, th01, ctA0, stA0, ctA1, stA1, fB[0], fB[1]);
        sim_pair(b1.x, b1.y, th02, th03, ctB0, stB0, ctB1, stB1, fB[2], fB[3]);

#pragma unroll
        for (int c = 0; c < NC; ++c) {
            const float4 w4 = *(const float4*)(W + c * 784 + p * 4);
            accA[c] = fmaf(fA[0], w4.x, fmaf(fA[1], w4.y,
                      fmaf(fA[2], w4.z, fmaf(fA[3], w4.w, accA[c]))));
            accB[c] = fmaf(fB[0], w4.x, fmaf(fB[1], w4.y,
                      fmaf(fB[2], w4.z, fmaf(fB[3], w4.w, accB[c]))));
        }
    }

    // xor-butterfly reduce: afterwards EVERY lane holds the full per-class sums
#pragma unroll
    for (int c = 0; c < NC; ++c) {
        float vA = accA[c], vB = accB[c];
#pragma unroll
        for (int m = 1; m < 64; m <<= 1) {
            vA += __shfl_xor(vA, m);
            vB += __shfl_xor(vB, m);
        }
        accA[c] = vA + s_bias[c];
        accB[c] = vB + s_bias[c];
    }

    // lanes <32 take image A, lanes >=32 take image B; softmax in-register
    float lg[NC];
#pragma unroll
    for (int c = 0; c < NC; ++c) lg[c] = (lane < 32) ? accA[c] : accB[c];

    float m = lg[0];
#pragma unroll
    for (int c = 1; c < NC; ++c) m = fmaxf(m, lg[c]);
    float se = 0.f;
#pragma unroll
    for (int c = 0; c < NC; ++c) se += __expf(lg[c] - m);
    const float lse = m + __logf(se);

    const int wl = lane & 31;
    const int img = imgA + (lane >> 5);
    if (wl < NC) out[img * NC + wl] = lg[wl] - lse;
}

extern "C" void kernel_launch(void* const* d_in, const int* in_sizes, int n_in,
                              void* d_out, int out_size, void* d_ws, size_t ws_size,
                              hipStream_t stream) {
    const float* x     = (const float*)d_in[0];  // (B,1,28,28)
    const float* theta = (const float*)d_in[1];  // (2,4)
    const float* W     = (const float*)d_in[2];  // (10,784)
    const float* bias  = (const float*)d_in[3];  // (10,)
    float* out = (float*)d_out;                  // (B,10)
    const int B = in_sizes[0] / 784;
    const int waves = (B + 1) / 2;               // 2 images per wave
    const int blocks = (waves + 3) / 4;          // 4 waves per block
    quanv_fused<<<blocks, 256, 0, stream>>>(x, theta, W, bias, out, B);
}

// Round 3
// 15.595 us; speedup vs baseline: 2.0457x; 1.0923x over previous
//
#include <hip/hip_runtime.h>
#include <math.h>

#define NP 196   // patches per image
#define NC 10    // classes

// One wave = FOUR images. Lane l handles patches {l, l+64, l+128} (+192+l for
// l<4) for all 4 images; W float4 loads amortize over 4 images.
// Logit reduction: xor32 merge (A,B)->mAB, (C,D)->mCD (1 shuffle/class each),
// xor16 merge -> m4 (row r holds image {A,C,B,D}[r]); masks 8,4,2,1 via DPP
// adds on the VALU pipe. Softmax per 16-lane row, all in registers. No LDS
// arrays, no __syncthreads.

template<int CTRL>
__device__ __forceinline__ float dpp_add(float v) {
    int t = __builtin_amdgcn_update_dpp(0, __float_as_int(v), CTRL, 0xF, 0xF, true);
    return v + __int_as_float(t);
}

__device__ __forceinline__ float swz_xor16_add(float v) {
    // BitMode: lane' = ((lane & 0x1F) | 0) ^ 16  (within each 32-lane half)
    int t = __builtin_amdgcn_ds_swizzle(__float_as_int(v), 0x401F);
    return v + __int_as_float(t);
}

__device__ __forceinline__ void sim_pair(float pxa, float pxb,
                                         float th0a, float th0b,
                                         float ct0, float st0,
                                         float ct1, float st1,
                                         float& z0, float& z1) {
    float sa, ca, sb, cb;
    __sincosf(0.5f * (pxa + th0a), &sa, &ca);
    __sincosf(0.5f * (pxb + th0b), &sb, &cb);
    float p0 = ca * cb, p1 = ca * sb, p2 = sa * sb, p3 = sa * cb;
    float q0 = ct0 * p0 - st0 * p2, q2 = st0 * p0 + ct0 * p2;
    float q1 = ct0 * p1 - st0 * p3, q3 = st0 * p1 + ct0 * p3;
    float r0 = ct1 * q0 - st1 * q1, r1 = st1 * q0 + ct1 * q1;
    float r2 = ct1 * q2 - st1 * q3, r3 = st1 * q2 + ct1 * q3;
    float e0 = r0 * r0, e1 = r1 * r1, e2 = r2 * r2, e3 = r3 * r3;
    z0 = (e0 + e1) - (e2 + e3);
    z1 = (e0 - e1) + (e3 - e2);
}

__global__ __launch_bounds__(256, 2) void quanv_fused(
    const float* __restrict__ x,      // (B, 784)
    const float* __restrict__ theta,  // (2, 4)
    const float* __restrict__ W,      // (10, 784)
    const float* __restrict__ bias,   // (10,)
    float* __restrict__ out,          // (B, 10)
    int B)
{
    const int tid  = threadIdx.x;
    const int lane = tid & 63;
    const int wave = blockIdx.x * 4 + (tid >> 6);
    const int imgbase = wave * 4;
    if (imgbase >= B) return;

    // uniform scalar loads (s_load) — no LDS, no syncthreads
    const float th00 = theta[0], th01 = theta[1], th02 = theta[2], th03 = theta[3];
    float ct[4], st[4];
#pragma unroll
    for (int w = 0; w < 4; ++w) __sincosf(0.5f * theta[4 + w], &st[w], &ct[w]);

    const float* x0 = x + (size_t)imgbase * 784;

    float acc[4][NC];
#pragma unroll
    for (int m = 0; m < 4; ++m)
#pragma unroll
        for (int c = 0; c < NC; ++c) acc[m][c] = 0.f;

#pragma unroll
    for (int k = 0; k < 4; ++k) {
        const bool active = (k < 3) || (lane < 4);
        const int p = lane + 64 * k;
        const int pi = p / 14;
        const int pj = p - pi * 14;
        const int off = pi * 56 + pj * 2;

        float f[4][4];
        if (active) {
#pragma unroll
            for (int m = 0; m < 4; ++m) {
                const float* xm = x0 + m * 784 + off;
                const float2 r0 = *(const float2*)(xm);
                const float2 r1 = *(const float2*)(xm + 28);
                sim_pair(r0.x, r0.y, th00, th01, ct[0], st[0], ct[1], st[1],
                         f[m][0], f[m][1]);
                sim_pair(r1.x, r1.y, th02, th03, ct[2], st[2], ct[3], st[3],
                         f[m][2], f[m][3]);
            }
#pragma unroll
            for (int c = 0; c < NC; ++c) {
                const float4 w4 = *(const float4*)(W + c * 784 + p * 4);
#pragma unroll
                for (int m = 0; m < 4; ++m) {
                    acc[m][c] = fmaf(f[m][0], w4.x, fmaf(f[m][1], w4.y,
                                fmaf(f[m][2], w4.z, fmaf(f[m][3], w4.w, acc[m][c]))));
                }
            }
        }
    }

    // ---- reduction ----
    const bool lo32 = (lane & 32) == 0;
    const bool lo16 = (lane & 16) == 0;
    float m4[NC];
#pragma unroll
    for (int c = 0; c < NC; ++c) {
        // xor-32 merge: mAB lanes<32 = image0 half-sum, lanes>=32 = image1
        float tAB = lo32 ? acc[0][c] : acc[1][c];
        float uAB = lo32 ? acc[1][c] : acc[0][c];
        float mAB = tAB + __shfl_xor(uAB, 32);
        float tCD = lo32 ? acc[2][c] : acc[3][c];
        float uCD = lo32 ? acc[3][c] : acc[2][c];
        float mCD = tCD + __shfl_xor(uCD, 32);
        // xor-16 merge: m4 rows (0,1,2,3) -> images (0, 2, 1, 3)
        float t = lo16 ? mAB : mCD;
        float u = lo16 ? mCD : mAB;
        float v = t + swz_xor16_add(u) - u;   // t + swizzle16(u)
        // within-16 reduce on VALU pipe: ror4, ror8, qp_xor1, qp_xor2
        v = dpp_add<0x124>(v);   // row_ror:4
        v = dpp_add<0x128>(v);   // row_ror:8
        v = dpp_add<0xB1>(v);    // quad_perm [1,0,3,2] == xor 1
        v = dpp_add<0x4E>(v);    // quad_perm [2,3,0,1] == xor 2
        m4[c] = v + bias[c];
    }

    // ---- softmax per 16-lane row (row owns one image) ----
    float mx = m4[0];
#pragma unroll
    for (int c = 1; c < NC; ++c) mx = fmaxf(mx, m4[c]);
    float se = 0.f;
#pragma unroll
    for (int c = 0; c < NC; ++c) se += __expf(m4[c] - mx);
    const float lse = mx + __logf(se);

    const int r  = lane >> 4;
    const int cl = lane & 15;
    const int img = imgbase + ((r & 1) << 1) + (r >> 1);
    float val = m4[0];
#pragma unroll
    for (int c = 1; c < NC; ++c) val = (cl == c) ? m4[c] : val;
    if (cl < NC) out[img * NC + cl] = val - lse;
}

extern "C" void kernel_launch(void* const* d_in, const int* in_sizes, int n_in,
                              void* d_out, int out_size, void* d_ws, size_t ws_size,
                              hipStream_t stream) {
    const float* x     = (const float*)d_in[0];  // (B,1,28,28)
    const float* theta = (const float*)d_in[1];  // (2,4)
    const float* W     = (const float*)d_in[2];  // (10,784)
    const float* bias  = (const float*)d_in[3];  // (10,)
    float* out = (float*)d_out;                  // (B,10)
    const int B = in_sizes[0] / 784;
    const int waves  = (B + 3) / 4;              // 4 images per wave
    const int blocks = (waves + 3) / 4;          // 4 waves per block
    quanv_fused<<<blocks, 256, 0, stream>>>(x, theta, W, bias, out, B);
}